// Round 11
// baseline (696.145 us; speedup 1.0000x reference)
//
#include <hip/hip_runtime.h>
#include <cmath>

#define NN 200000
#define EE 6400000
#define CSH 8             // bucket = col >> 8 (256 nodes/bucket)
#define BSZ 256           // nodes per bucket
#define NBKT 782          // ceil(200000 / 256)
#define GRID_A 512        // blocks in phase-A kernels (MUST match scan width)
#define BLK_A 256
#define RB_SHIFT 14       // row band = row >> 14 (16384 rows/band; y1 slice 1.57 MB, L2-fit)
#define NRB 13            // ceil(200000 / 16384)

// monotone float<->uint encoding: enc preserves order under unsigned max.
// Inter-layer y buffers are stored PRE-ENCODED: the gather hot loop does zero
// per-edge encode VALU; guarded LDS atomicMax on raw loaded words.
__device__ __forceinline__ unsigned int fenc(float f) {
    unsigned int u = __float_as_uint(f);
    return (u & 0x80000000u) ? ~u : (u | 0x80000000u);
}
__device__ __forceinline__ float fdec(unsigned int u) {
    unsigned int v = (u & 0x80000000u) ? (u & 0x7FFFFFFFu) : ~u;
    return __uint_as_float(v);
}

// =============== Phase A: bucket edges by col>>CSH (counting sort, LDS atomics only) ===============

__global__ __launch_bounds__(BLK_A) void count_buckets_kernel(const int* __restrict__ col,
                                                              int* __restrict__ blkhist) {
    __shared__ int h[NBKT];
    for (int t = threadIdx.x; t < NBKT; t += BLK_A) h[t] = 0;
    __syncthreads();
    const int4* col4 = (const int4*)col;
    for (int i = blockIdx.x * BLK_A + threadIdx.x; i < EE / 4; i += GRID_A * BLK_A) {
        int4 c = col4[i];
        atomicAdd(&h[c.x >> CSH], 1);
        atomicAdd(&h[c.y >> CSH], 1);
        atomicAdd(&h[c.z >> CSH], 1);
        atomicAdd(&h[c.w >> CSH], 1);
    }
    __syncthreads();
    for (int t = threadIdx.x; t < NBKT; t += BLK_A) blkhist[blockIdx.x * NBKT + t] = h[t];
}

__global__ __launch_bounds__(GRID_A) void scan_cols_kernel(int* __restrict__ blkhist,
                                                           int* __restrict__ btot) {
    __shared__ int sc[GRID_A];
    int bkt = blockIdx.x, t = threadIdx.x;
    int v = blkhist[t * NBKT + bkt];
    sc[t] = v;
    __syncthreads();
    for (int off = 1; off < GRID_A; off <<= 1) {
        int add = (t >= off) ? sc[t - off] : 0;
        __syncthreads();
        sc[t] += add;
        __syncthreads();
    }
    blkhist[t * NBKT + bkt] = sc[t] - v;  // exclusive along blocks
    if (t == GRID_A - 1) btot[bkt] = sc[t];
}

__global__ __launch_bounds__(1024) void scan_btot_kernel(const int* __restrict__ btot,
                                                         int* __restrict__ bbase) {
    __shared__ int sc[1024];
    int t = threadIdx.x;
    int v = (t < NBKT) ? btot[t] : 0;
    sc[t] = v;
    __syncthreads();
    for (int off = 1; off < 1024; off <<= 1) {
        int add = (t >= off) ? sc[t - off] : 0;
        __syncthreads();
        sc[t] += add;
        __syncthreads();
    }
    if (t < NBKT) bbase[t] = sc[t] - v;
    if (t == NBKT - 1) bbase[NBKT] = sc[t];  // total = EE
}

// A3: place packed codes (int4 edge loads). code = (col&255)<<18 | row  (row < 2^18)
__global__ __launch_bounds__(BLK_A) void place_pairs_kernel(const int* __restrict__ row,
                                                            const int* __restrict__ col,
                                                            const int* __restrict__ blkhist,
                                                            const int* __restrict__ bbase,
                                                            unsigned int* __restrict__ pairs) {
    __shared__ int cur[NBKT];
    for (int t = threadIdx.x; t < NBKT; t += BLK_A)
        cur[t] = bbase[t] + blkhist[blockIdx.x * NBKT + t];
    __syncthreads();
    const int4* col4 = (const int4*)col;
    const int4* row4 = (const int4*)row;
    for (int i = blockIdx.x * BLK_A + threadIdx.x; i < EE / 4; i += GRID_A * BLK_A) {
        int4 c = col4[i];
        int4 r = row4[i];
        int p0 = atomicAdd(&cur[c.x >> CSH], 1);
        pairs[p0] = (unsigned int)r.x | ((unsigned int)(c.x & (BSZ - 1)) << 18);
        int p1 = atomicAdd(&cur[c.y >> CSH], 1);
        pairs[p1] = (unsigned int)r.y | ((unsigned int)(c.y & (BSZ - 1)) << 18);
        int p2 = atomicAdd(&cur[c.z >> CSH], 1);
        pairs[p2] = (unsigned int)r.z | ((unsigned int)(c.z & (BSZ - 1)) << 18);
        int p3 = atomicAdd(&cur[c.w >> CSH], 1);
        pairs[p3] = (unsigned int)r.w | ((unsigned int)(c.w & (BSZ - 1)) << 18);
    }
}

// A4: per-bucket counting sort into BAND-MAJOR order (band = row>>RB_SHIFT).
__global__ __launch_bounds__(512) void bucket_build_band_kernel(const unsigned int* __restrict__ pairs,
                                                                const int* __restrict__ bbase,
                                                                float* __restrict__ dinv,
                                                                unsigned int* __restrict__ codes,
                                                                int* __restrict__ bandoffs) {
    __shared__ int bin[BSZ * NRB];   // 3328: flat band-major, linear n = bb*BSZ + lc
    __shared__ int sc[512];
    int b = blockIdx.x, tid = threadIdx.x;
    int base = bbase[b], end = bbase[b + 1];
    int node0 = b << CSH;
    int nloc = NN - node0; if (nloc > BSZ) nloc = BSZ;

    for (int t = tid; t < BSZ * NRB; t += 512) bin[t] = 0;
    __syncthreads();
    for (int i = base + tid; i < end; i += 512) {
        unsigned int p = pairs[i];
        int lc = p >> 18;
        int rw = (int)(p & 0x3FFFFu);
        atomicAdd(&bin[(rw >> RB_SHIFT) * BSZ + lc], 1);
    }
    __syncthreads();

    // degree -> dinv (read before positions overwrite bins)
    if (tid < nloc) {
        int d = 0;
#pragma unroll
        for (int bb = 0; bb < NRB; ++bb) d += bin[bb * BSZ + tid];
        dinv[node0 + tid] = rsqrtf((float)(d + 1));  // +1 self loop
    }
    __syncthreads();

    // exclusive scan of the flat 3328 array: thread t<BSZ owns chunk [t*NRB, t*NRB+NRB)
    int tot = 0;
    if (tid < BSZ) {
#pragma unroll
        for (int i = 0; i < NRB; ++i) tot += bin[tid * NRB + i];
    }
    sc[tid] = tot;
    __syncthreads();
    for (int off = 1; off < 512; off <<= 1) {
        int add = (tid >= off) ? sc[tid - off] : 0;
        __syncthreads();
        sc[tid] += add;
        __syncthreads();
    }
    if (tid < BSZ) {
        int run = base + sc[tid] - tot;   // global exclusive base of this chunk
#pragma unroll
        for (int i = 0; i < NRB; ++i) {
            int c = bin[tid * NRB + i];
            bin[tid * NRB + i] = run;     // becomes placement cursor
            run += c;
        }
    }
    __syncthreads();

    if (tid < NRB) bandoffs[b * (NRB + 1) + tid] = bin[tid * BSZ];
    if (tid == 0) bandoffs[b * (NRB + 1) + NRB] = end;
    __syncthreads();

    for (int i = base + tid; i < end; i += 512) {
        unsigned int p = pairs[i];
        int lc = p >> 18;
        int rw = (int)(p & 0x3FFFFu);
        int pos = atomicAdd(&bin[(rw >> RB_SHIFT) * BSZ + lc], 1);
        codes[pos] = p;
    }
}

// =============== layer-1 matmul, epilogue premultiplies dinv AND ENCODES: y = fenc(dinv*(x@W)) =======
__global__ void matmul128_y_kernel(const float* __restrict__ x, const float* __restrict__ W,
                                   const float* __restrict__ dinv, unsigned int* __restrict__ y, int n) {
    __shared__ float Ws[128 * 24];
    for (int t = threadIdx.x; t < 128 * 24; t += blockDim.x) Ws[t] = W[t];
    __syncthreads();
    int i = blockIdx.x * blockDim.x + threadIdx.x;
    if (i >= n) return;
    float acc[24];
#pragma unroll
    for (int j = 0; j < 24; ++j) acc[j] = 0.f;
    const float4* hr = (const float4*)(x + (size_t)i * 128);
#pragma unroll 8
    for (int k4 = 0; k4 < 32; ++k4) {
        float4 hv = hr[k4];
        const float* wk = &Ws[k4 * 4 * 24];
#pragma unroll
        for (int j = 0; j < 24; ++j) acc[j] += hv.x * wk[j];
#pragma unroll
        for (int j = 0; j < 24; ++j) acc[j] += hv.y * wk[24 + j];
#pragma unroll
        for (int j = 0; j < 24; ++j) acc[j] += hv.z * wk[48 + j];
#pragma unroll
        for (int j = 0; j < 24; ++j) acc[j] += hv.w * wk[72 + j];
    }
    float di = dinv[i];
    uint4* orow = (uint4*)(y + (size_t)i * 24);
#pragma unroll
    for (int q = 0; q < 6; ++q) {
        uint4 o;
        o.x = fenc(di * acc[q * 4 + 0]);
        o.y = fenc(di * acc[q * 4 + 1]);
        o.z = fenc(di * acc[q * 4 + 2]);
        o.w = fenc(di * acc[q * 4 + 3]);
        orow[q] = o;
    }
}

// =============== band-phased bucket gather on PRE-ENCODED y: GUARDED ds_max_u32 ======================
// 256-node buckets, 782 blocks x 512 threads, all co-resident (r10). PHASES
// template: 13 band phases (lockstep L2 sweep) for big y tables; PHASES=1 (no
// inner barriers, codes order irrelevant for max) when y fits per-XCD L2
// outright (y4 3.2MB, y5 1.6MB) - banding there was pure barrier overhead.
// Hot loop identical to r8/r10: guarded atomics (r6 lesson), odd per-node LDS
// stride (r5), pre-encoded y (r8), per-lane whole-row gather (r9 reverted).
template<int DOUT, int DNEXT, bool FINAL, int PHASES>
__global__ __launch_bounds__(512) void gather_band_kernel(const unsigned int* __restrict__ codes,
                                                          const int* __restrict__ bandoffs,
                                                          const float* __restrict__ dinv,
                                                          const unsigned int* __restrict__ y,  // encoded
                                                          const float* __restrict__ bias,
                                                          const float* __restrict__ Wn,
                                                          const float* __restrict__ bcls,
                                                          float* __restrict__ outp,   // encoded when !FINAL
                                                          float* __restrict__ hout) {
    constexpr int ST = DOUT + 1;           // odd stride -> conflict-free random access
    __shared__ unsigned int acc[BSZ * ST];
    __shared__ float dcs[BSZ];
    __shared__ float Ws[DOUT * DNEXT];
    __shared__ float bs[DOUT];
    const int b0 = blockIdx.x;
    const int node0 = b0 << CSH;
    const int nloc = (NN - node0 < BSZ) ? (NN - node0) : BSZ;
    const int tid = threadIdx.x;

    if (tid < DOUT * DNEXT) Ws[tid] = Wn[tid];
    if (tid < DOUT) bs[tid] = bias[tid];
    if (tid < nloc) dcs[tid] = dinv[node0 + tid];
    for (int idx = tid; idx < nloc * DOUT; idx += 512) {
        int lc = idx / DOUT;
        int f  = idx - lc * DOUT;
        acc[lc * ST + f] = y[(size_t)node0 * DOUT + idx];   // self-loop seed (already encoded)
    }
    __syncthreads();

    const int* bo = bandoffs + b0 * (NRB + 1);
#pragma unroll 1
    for (int ph = 0; ph < PHASES; ++ph) {
        const int s0 = (PHASES == 1) ? bo[0] : bo[ph];
        const int e  = (PHASES == 1) ? bo[NRB] : bo[ph + 1];
        for (int i = s0 + tid; i < e; i += 1024) {
            const int i2 = i + 512;
            const bool two = (i2 < e);
            unsigned int p0 = codes[i];
            size_t r0 = (size_t)(p0 & 0x3FFFFu);
            unsigned int* a0 = &acc[(p0 >> 18) * ST];
            unsigned int p1 = 0; unsigned int* a1 = nullptr;
            if constexpr (DOUT % 4 == 0) {
                constexpr int NQ = DOUT / 4;
                const uint4* y0 = (const uint4*)(y + r0 * DOUT);
                uint4 c0[NQ];
#pragma unroll
                for (int q = 0; q < NQ; ++q) c0[q] = y0[q];
                uint4 c1[NQ];
                if (two) {
                    p1 = codes[i2];
                    size_t r1 = (size_t)(p1 & 0x3FFFFu);
                    const uint4* y1 = (const uint4*)(y + r1 * DOUT);
#pragma unroll
                    for (int q = 0; q < NQ; ++q) c1[q] = y1[q];
                    a1 = &acc[(p1 >> 18) * ST];
                }
#pragma unroll
                for (int q = 0; q < NQ; ++q) {
                    if (c0[q].x > a0[q * 4 + 0]) atomicMax(&a0[q * 4 + 0], c0[q].x);
                    if (c0[q].y > a0[q * 4 + 1]) atomicMax(&a0[q * 4 + 1], c0[q].y);
                    if (c0[q].z > a0[q * 4 + 2]) atomicMax(&a0[q * 4 + 2], c0[q].z);
                    if (c0[q].w > a0[q * 4 + 3]) atomicMax(&a0[q * 4 + 3], c0[q].w);
                }
                if (two) {
#pragma unroll
                    for (int q = 0; q < NQ; ++q) {
                        if (c1[q].x > a1[q * 4 + 0]) atomicMax(&a1[q * 4 + 0], c1[q].x);
                        if (c1[q].y > a1[q * 4 + 1]) atomicMax(&a1[q * 4 + 1], c1[q].y);
                        if (c1[q].z > a1[q * 4 + 2]) atomicMax(&a1[q * 4 + 2], c1[q].z);
                        if (c1[q].w > a1[q * 4 + 3]) atomicMax(&a1[q * 4 + 3], c1[q].w);
                    }
                }
            } else {
                constexpr int NQ = DOUT / 2;
                const uint2* y0 = (const uint2*)(y + r0 * DOUT);
                uint2 c0[NQ];
#pragma unroll
                for (int q = 0; q < NQ; ++q) c0[q] = y0[q];
                uint2 c1[NQ];
                if (two) {
                    p1 = codes[i2];
                    size_t r1 = (size_t)(p1 & 0x3FFFFu);
                    const uint2* y1 = (const uint2*)(y + r1 * DOUT);
#pragma unroll
                    for (int q = 0; q < NQ; ++q) c1[q] = y1[q];
                    a1 = &acc[(p1 >> 18) * ST];
                }
#pragma unroll
                for (int q = 0; q < NQ; ++q) {
                    if (c0[q].x > a0[q * 2 + 0]) atomicMax(&a0[q * 2 + 0], c0[q].x);
                    if (c0[q].y > a0[q * 2 + 1]) atomicMax(&a0[q * 2 + 1], c0[q].y);
                }
                if (two) {
#pragma unroll
                    for (int q = 0; q < NQ; ++q) {
                        if (c1[q].x > a1[q * 2 + 0]) atomicMax(&a1[q * 2 + 0], c1[q].x);
                        if (c1[q].y > a1[q * 2 + 1]) atomicMax(&a1[q * 2 + 1], c1[q].y);
                    }
                }
            }
        }
        __syncthreads();   // band phase barrier (once total when PHASES==1)
    }

    // decode + tanh in place (float bits through the same padded layout)
    float* hsf = (float*)acc;
    for (int idx = tid; idx < nloc * DOUT; idx += 512) {
        int lc = idx / DOUT;
        int f  = idx - lc * DOUT;
        hsf[lc * ST + f] = tanhf(dcs[lc] * fdec(acc[lc * ST + f]) + bs[f]);
    }
    __syncthreads();

    if constexpr (!FINAL) {
        unsigned int* outu = (unsigned int*)outp;
        for (int idx = tid; idx < nloc * DNEXT; idx += 512) {
            int lc = idx / DNEXT;
            int j = idx - lc * DNEXT;
            float a = 0.f;
#pragma unroll
            for (int k = 0; k < DOUT; ++k) a += hsf[lc * ST + k] * Ws[k * DNEXT + j];
            outu[(size_t)node0 * DNEXT + idx] = fenc(dcs[lc] * a);
        }
    } else {
        for (int lc = tid; lc < nloc; lc += 512) {
            float h0 = hsf[lc * ST], h1 = hsf[lc * ST + 1];
            float2 ho; ho.x = h0; ho.y = h1;
            ((float2*)hout)[node0 + lc] = ho;
            float4 o;
            o.x = h0 * Ws[0] + h1 * Ws[DNEXT + 0] + bcls[0];
            o.y = h0 * Ws[1] + h1 * Ws[DNEXT + 1] + bcls[1];
            o.z = h0 * Ws[2] + h1 * Ws[DNEXT + 2] + bcls[2];
            o.w = h0 * Ws[3] + h1 * Ws[DNEXT + 3] + bcls[3];
            ((float4*)outp)[node0 + lc] = o;
        }
    }
}

extern "C" void kernel_launch(void* const* d_in, const int* in_sizes, int n_in,
                              void* d_out, int out_size, void* d_ws, size_t ws_size,
                              hipStream_t stream) {
    const float* x  = (const float*)d_in[0];
    const int*   ei = (const int*)d_in[1];
    const int* row = ei;            // edge_index[0] = source
    const int* col = ei + EE;       // edge_index[1] = target
    const float* W1 = (const float*)d_in[2];  const float* b1 = (const float*)d_in[3];
    const float* W2 = (const float*)d_in[4];  const float* b2 = (const float*)d_in[5];
    const float* W3 = (const float*)d_in[6];  const float* b3 = (const float*)d_in[7];
    const float* W4 = (const float*)d_in[8];  const float* b4 = (const float*)d_in[9];
    const float* W5 = (const float*)d_in[10]; const float* b5 = (const float*)d_in[11];
    const float* Wc = (const float*)d_in[12]; const float* bc = (const float*)d_in[13];
    float* out = (float*)d_out;

    // ---- workspace carve (identical offsets to r10, tripwire-proven) ----
    // pairs is dead before matmul128_y writes bufB -> alias them. codes persists all layers.
    char* ws = (char*)d_ws;
    float*        dinv       = (float*)(ws + 0);                //    800,000
    int*          bandoffs   = (int*)(ws + 800000);             //     43,792 (NBKT*(NRB+1)) -> pad 81,408
    int*          bbase      = (int*)(ws + 881408);             //      3,132 -> pad 3,200
    int*          btot       = (int*)(ws + 884608);             //      3,128 -> pad 3,200
    int*          blkhist    = (int*)(ws + 887808);             //  1,601,536 (GRID_A*NBKT ints)
    unsigned int* codes      = (unsigned int*)(ws + 2489344);   // 25,600,000
    unsigned int* pairs      = (unsigned int*)(ws + 28089344);  // 25,600,000
    unsigned int* bufB       = (unsigned int*)(ws + 28089344);  // (aliases pairs; y1/y3/y5, ENCODED)
    unsigned int* bufA       = (unsigned int*)(ws + 53689344);  // 19,200,000 (y2/y4, ENCODED)
    // total: 72,889,344 B

    const int BLK = 256;
    const int gN = (NN + BLK - 1) / BLK;       // 782

    // ---- CSR build: two-level counting sort; adjacency emitted band-major per bucket ----
    count_buckets_kernel<<<GRID_A, BLK_A, 0, stream>>>(col, blkhist);
    scan_cols_kernel<<<NBKT, GRID_A, 0, stream>>>(blkhist, btot);
    scan_btot_kernel<<<1, 1024, 0, stream>>>(btot, bbase);
    place_pairs_kernel<<<GRID_A, BLK_A, 0, stream>>>(row, col, blkhist, bbase, pairs);
    bucket_build_band_kernel<<<NBKT, 512, 0, stream>>>(pairs, bbase, dinv, codes, bandoffs);

    // ---- layer 1 matmul: y1 = fenc(dinv * (x @ W1)), [N,24] encoded ----
    matmul128_y_kernel<<<gN, BLK, 0, stream>>>(x, W1, dinv, bufB, NN);

    // ---- layer 1 gather + layer-2 matmul fused: y2 [N,12] encoded (banded: y1 19.2MB) ----
    gather_band_kernel<24, 12, false, NRB><<<NBKT, 512, 0, stream>>>(
        codes, bandoffs, dinv, bufB, b1, W2, nullptr, (float*)bufA, nullptr);
    // ---- layer 2 gather + layer-3 matmul fused: y3 [N,6] encoded (banded: y2 9.6MB) ----
    gather_band_kernel<12, 6, false, NRB><<<NBKT, 512, 0, stream>>>(
        codes, bandoffs, dinv, bufA, b2, W3, nullptr, (float*)bufB, nullptr);
    // ---- layer 3 gather + layer-4 matmul fused: y4 [N,4] encoded (banded: y3 4.8MB) ----
    gather_band_kernel<6, 4, false, NRB><<<NBKT, 512, 0, stream>>>(
        codes, bandoffs, dinv, bufB, b3, W4, nullptr, (float*)bufA, nullptr);
    // ---- layer 4 gather + layer-5 matmul fused: y5 [N,2] encoded (single-phase: y4 3.2MB L2-fit) ----
    gather_band_kernel<4, 2, false, 1><<<NBKT, 512, 0, stream>>>(
        codes, bandoffs, dinv, bufA, b4, W5, nullptr, (float*)bufB, nullptr);
    // ---- layer 5 gather + classifier fused: out [N,4], h [N,2] (single-phase: y5 1.6MB L2-fit) ----
    gather_band_kernel<2, 4, true, 1><<<NBKT, 512, 0, stream>>>(
        codes, bandoffs, dinv, bufB, b5, Wc, bc, out, out + (size_t)NN * 4);
}

// Round 12
// 677.684 us; speedup vs baseline: 1.0272x; 1.0272x over previous
//
#include <hip/hip_runtime.h>
#include <cmath>

#define NN 200000
#define EE 6400000
#define CSH 8             // bucket = col >> 8 (256 nodes/bucket)
#define BSZ 256           // nodes per bucket
#define NBKT 782          // ceil(200000 / 256)
#define GRID_A 512        // blocks in phase-A kernels (MUST match scan width)
#define BLK_A 256
#define RB_SHIFT 13       // row band = row >> 13 (8192 rows/band; y1 slice 0.79 MB, L2-fit) [r10-proven]
#define NRB 25            // ceil(200000 / 8192)

// monotone float<->uint encoding: enc preserves order under unsigned max.
// Inter-layer y buffers are stored PRE-ENCODED: the gather hot loop does zero
// per-edge encode VALU; guarded LDS atomicMax on raw loaded words.
__device__ __forceinline__ unsigned int fenc(float f) {
    unsigned int u = __float_as_uint(f);
    return (u & 0x80000000u) ? ~u : (u | 0x80000000u);
}
__device__ __forceinline__ float fdec(unsigned int u) {
    unsigned int v = (u & 0x80000000u) ? (u & 0x7FFFFFFFu) : ~u;
    return __uint_as_float(v);
}

// =============== Phase A: bucket edges by col>>CSH (counting sort, LDS atomics only) ===============

__global__ __launch_bounds__(BLK_A) void count_buckets_kernel(const int* __restrict__ col,
                                                              int* __restrict__ blkhist) {
    __shared__ int h[NBKT];
    for (int t = threadIdx.x; t < NBKT; t += BLK_A) h[t] = 0;
    __syncthreads();
    const int4* col4 = (const int4*)col;
    for (int i = blockIdx.x * BLK_A + threadIdx.x; i < EE / 4; i += GRID_A * BLK_A) {
        int4 c = col4[i];
        atomicAdd(&h[c.x >> CSH], 1);
        atomicAdd(&h[c.y >> CSH], 1);
        atomicAdd(&h[c.z >> CSH], 1);
        atomicAdd(&h[c.w >> CSH], 1);
    }
    __syncthreads();
    for (int t = threadIdx.x; t < NBKT; t += BLK_A) blkhist[blockIdx.x * NBKT + t] = h[t];
}

__global__ __launch_bounds__(GRID_A) void scan_cols_kernel(int* __restrict__ blkhist,
                                                           int* __restrict__ btot) {
    __shared__ int sc[GRID_A];
    int bkt = blockIdx.x, t = threadIdx.x;
    int v = blkhist[t * NBKT + bkt];
    sc[t] = v;
    __syncthreads();
    for (int off = 1; off < GRID_A; off <<= 1) {
        int add = (t >= off) ? sc[t - off] : 0;
        __syncthreads();
        sc[t] += add;
        __syncthreads();
    }
    blkhist[t * NBKT + bkt] = sc[t] - v;  // exclusive along blocks
    if (t == GRID_A - 1) btot[bkt] = sc[t];
}

__global__ __launch_bounds__(1024) void scan_btot_kernel(const int* __restrict__ btot,
                                                         int* __restrict__ bbase) {
    __shared__ int sc[1024];
    int t = threadIdx.x;
    int v = (t < NBKT) ? btot[t] : 0;
    sc[t] = v;
    __syncthreads();
    for (int off = 1; off < 1024; off <<= 1) {
        int add = (t >= off) ? sc[t - off] : 0;
        __syncthreads();
        sc[t] += add;
        __syncthreads();
    }
    if (t < NBKT) bbase[t] = sc[t] - v;
    if (t == NBKT - 1) bbase[NBKT] = sc[t];  // total = EE
}

// A3: place packed codes (int4 edge loads). code = (col&255)<<18 | row  (row < 2^18)
__global__ __launch_bounds__(BLK_A) void place_pairs_kernel(const int* __restrict__ row,
                                                            const int* __restrict__ col,
                                                            const int* __restrict__ blkhist,
                                                            const int* __restrict__ bbase,
                                                            unsigned int* __restrict__ pairs) {
    __shared__ int cur[NBKT];
    for (int t = threadIdx.x; t < NBKT; t += BLK_A)
        cur[t] = bbase[t] + blkhist[blockIdx.x * NBKT + t];
    __syncthreads();
    const int4* col4 = (const int4*)col;
    const int4* row4 = (const int4*)row;
    for (int i = blockIdx.x * BLK_A + threadIdx.x; i < EE / 4; i += GRID_A * BLK_A) {
        int4 c = col4[i];
        int4 r = row4[i];
        int p0 = atomicAdd(&cur[c.x >> CSH], 1);
        pairs[p0] = (unsigned int)r.x | ((unsigned int)(c.x & (BSZ - 1)) << 18);
        int p1 = atomicAdd(&cur[c.y >> CSH], 1);
        pairs[p1] = (unsigned int)r.y | ((unsigned int)(c.y & (BSZ - 1)) << 18);
        int p2 = atomicAdd(&cur[c.z >> CSH], 1);
        pairs[p2] = (unsigned int)r.z | ((unsigned int)(c.z & (BSZ - 1)) << 18);
        int p3 = atomicAdd(&cur[c.w >> CSH], 1);
        pairs[p3] = (unsigned int)r.w | ((unsigned int)(c.w & (BSZ - 1)) << 18);
    }
}

// A4: per-bucket counting sort into BAND-MAJOR order (band = row>>RB_SHIFT).
__global__ __launch_bounds__(512) void bucket_build_band_kernel(const unsigned int* __restrict__ pairs,
                                                                const int* __restrict__ bbase,
                                                                float* __restrict__ dinv,
                                                                unsigned int* __restrict__ codes,
                                                                int* __restrict__ bandoffs) {
    __shared__ int bin[BSZ * NRB];   // 6400: flat band-major, linear n = bb*BSZ + lc
    __shared__ int sc[512];
    int b = blockIdx.x, tid = threadIdx.x;
    int base = bbase[b], end = bbase[b + 1];
    int node0 = b << CSH;
    int nloc = NN - node0; if (nloc > BSZ) nloc = BSZ;

    for (int t = tid; t < BSZ * NRB; t += 512) bin[t] = 0;
    __syncthreads();
    for (int i = base + tid; i < end; i += 512) {
        unsigned int p = pairs[i];
        int lc = p >> 18;
        int rw = (int)(p & 0x3FFFFu);
        atomicAdd(&bin[(rw >> RB_SHIFT) * BSZ + lc], 1);
    }
    __syncthreads();

    // degree -> dinv (read before positions overwrite bins)
    if (tid < nloc) {
        int d = 0;
#pragma unroll
        for (int bb = 0; bb < NRB; ++bb) d += bin[bb * BSZ + tid];
        dinv[node0 + tid] = rsqrtf((float)(d + 1));  // +1 self loop
    }
    __syncthreads();

    // exclusive scan of the flat 6400 array: thread t<BSZ owns chunk [t*NRB, t*NRB+NRB)
    int tot = 0;
    if (tid < BSZ) {
#pragma unroll
        for (int i = 0; i < NRB; ++i) tot += bin[tid * NRB + i];
    }
    sc[tid] = tot;
    __syncthreads();
    for (int off = 1; off < 512; off <<= 1) {
        int add = (tid >= off) ? sc[tid - off] : 0;
        __syncthreads();
        sc[tid] += add;
        __syncthreads();
    }
    if (tid < BSZ) {
        int run = base + sc[tid] - tot;   // global exclusive base of this chunk
#pragma unroll
        for (int i = 0; i < NRB; ++i) {
            int c = bin[tid * NRB + i];
            bin[tid * NRB + i] = run;     // becomes placement cursor
            run += c;
        }
    }
    __syncthreads();

    if (tid < NRB) bandoffs[b * (NRB + 1) + tid] = bin[tid * BSZ];
    if (tid == 0) bandoffs[b * (NRB + 1) + NRB] = end;
    __syncthreads();

    for (int i = base + tid; i < end; i += 512) {
        unsigned int p = pairs[i];
        int lc = p >> 18;
        int rw = (int)(p & 0x3FFFFu);
        int pos = atomicAdd(&bin[(rw >> RB_SHIFT) * BSZ + lc], 1);
        codes[pos] = p;
    }
}

// =============== layer-1 matmul, epilogue premultiplies dinv AND ENCODES: y = fenc(dinv*(x@W)) =======
__global__ void matmul128_y_kernel(const float* __restrict__ x, const float* __restrict__ W,
                                   const float* __restrict__ dinv, unsigned int* __restrict__ y, int n) {
    __shared__ float Ws[128 * 24];
    for (int t = threadIdx.x; t < 128 * 24; t += blockDim.x) Ws[t] = W[t];
    __syncthreads();
    int i = blockIdx.x * blockDim.x + threadIdx.x;
    if (i >= n) return;
    float acc[24];
#pragma unroll
    for (int j = 0; j < 24; ++j) acc[j] = 0.f;
    const float4* hr = (const float4*)(x + (size_t)i * 128);
#pragma unroll 8
    for (int k4 = 0; k4 < 32; ++k4) {
        float4 hv = hr[k4];
        const float* wk = &Ws[k4 * 4 * 24];
#pragma unroll
        for (int j = 0; j < 24; ++j) acc[j] += hv.x * wk[j];
#pragma unroll
        for (int j = 0; j < 24; ++j) acc[j] += hv.y * wk[24 + j];
#pragma unroll
        for (int j = 0; j < 24; ++j) acc[j] += hv.z * wk[48 + j];
#pragma unroll
        for (int j = 0; j < 24; ++j) acc[j] += hv.w * wk[72 + j];
    }
    float di = dinv[i];
    uint4* orow = (uint4*)(y + (size_t)i * 24);
#pragma unroll
    for (int q = 0; q < 6; ++q) {
        uint4 o;
        o.x = fenc(di * acc[q * 4 + 0]);
        o.y = fenc(di * acc[q * 4 + 1]);
        o.z = fenc(di * acc[q * 4 + 2]);
        o.w = fenc(di * acc[q * 4 + 3]);
        orow[q] = o;
    }
}

// =============== band-phased bucket gather on PRE-ENCODED y: GUARDED ds_max_u32 ======================
// 256-node buckets, 782 blocks x 512 threads, all co-resident (r10). PHASES
// template: NRB band phases (lockstep L2 sweep) for big y tables; PHASES=1 (no
// inner barriers, codes order irrelevant for max) when y fits per-XCD L2
// outright (y4 3.2MB, y5 1.6MB). RB_SHIFT=13 restored (r11's 14 cost +38% FETCH).
// Hot loop identical to r8/r10: guarded atomics (r6 lesson), odd per-node LDS
// stride (r5), pre-encoded y (r8), per-lane whole-row gather (r9 reverted).
template<int DOUT, int DNEXT, bool FINAL, int PHASES>
__global__ __launch_bounds__(512) void gather_band_kernel(const unsigned int* __restrict__ codes,
                                                          const int* __restrict__ bandoffs,
                                                          const float* __restrict__ dinv,
                                                          const unsigned int* __restrict__ y,  // encoded
                                                          const float* __restrict__ bias,
                                                          const float* __restrict__ Wn,
                                                          const float* __restrict__ bcls,
                                                          float* __restrict__ outp,   // encoded when !FINAL
                                                          float* __restrict__ hout) {
    constexpr int ST = DOUT + 1;           // odd stride -> conflict-free random access
    __shared__ unsigned int acc[BSZ * ST];
    __shared__ float dcs[BSZ];
    __shared__ float Ws[DOUT * DNEXT];
    __shared__ float bs[DOUT];
    const int b0 = blockIdx.x;
    const int node0 = b0 << CSH;
    const int nloc = (NN - node0 < BSZ) ? (NN - node0) : BSZ;
    const int tid = threadIdx.x;

    if (tid < DOUT * DNEXT) Ws[tid] = Wn[tid];
    if (tid < DOUT) bs[tid] = bias[tid];
    if (tid < nloc) dcs[tid] = dinv[node0 + tid];
    for (int idx = tid; idx < nloc * DOUT; idx += 512) {
        int lc = idx / DOUT;
        int f  = idx - lc * DOUT;
        acc[lc * ST + f] = y[(size_t)node0 * DOUT + idx];   // self-loop seed (already encoded)
    }
    __syncthreads();

    const int* bo = bandoffs + b0 * (NRB + 1);
#pragma unroll 1
    for (int ph = 0; ph < PHASES; ++ph) {
        const int s0 = (PHASES == 1) ? bo[0] : bo[ph];
        const int e  = (PHASES == 1) ? bo[NRB] : bo[ph + 1];
        for (int i = s0 + tid; i < e; i += 1024) {
            const int i2 = i + 512;
            const bool two = (i2 < e);
            unsigned int p0 = codes[i];
            size_t r0 = (size_t)(p0 & 0x3FFFFu);
            unsigned int* a0 = &acc[(p0 >> 18) * ST];
            unsigned int p1 = 0; unsigned int* a1 = nullptr;
            if constexpr (DOUT % 4 == 0) {
                constexpr int NQ = DOUT / 4;
                const uint4* y0 = (const uint4*)(y + r0 * DOUT);
                uint4 c0[NQ];
#pragma unroll
                for (int q = 0; q < NQ; ++q) c0[q] = y0[q];
                uint4 c1[NQ];
                if (two) {
                    p1 = codes[i2];
                    size_t r1 = (size_t)(p1 & 0x3FFFFu);
                    const uint4* y1 = (const uint4*)(y + r1 * DOUT);
#pragma unroll
                    for (int q = 0; q < NQ; ++q) c1[q] = y1[q];
                    a1 = &acc[(p1 >> 18) * ST];
                }
#pragma unroll
                for (int q = 0; q < NQ; ++q) {
                    if (c0[q].x > a0[q * 4 + 0]) atomicMax(&a0[q * 4 + 0], c0[q].x);
                    if (c0[q].y > a0[q * 4 + 1]) atomicMax(&a0[q * 4 + 1], c0[q].y);
                    if (c0[q].z > a0[q * 4 + 2]) atomicMax(&a0[q * 4 + 2], c0[q].z);
                    if (c0[q].w > a0[q * 4 + 3]) atomicMax(&a0[q * 4 + 3], c0[q].w);
                }
                if (two) {
#pragma unroll
                    for (int q = 0; q < NQ; ++q) {
                        if (c1[q].x > a1[q * 4 + 0]) atomicMax(&a1[q * 4 + 0], c1[q].x);
                        if (c1[q].y > a1[q * 4 + 1]) atomicMax(&a1[q * 4 + 1], c1[q].y);
                        if (c1[q].z > a1[q * 4 + 2]) atomicMax(&a1[q * 4 + 2], c1[q].z);
                        if (c1[q].w > a1[q * 4 + 3]) atomicMax(&a1[q * 4 + 3], c1[q].w);
                    }
                }
            } else {
                constexpr int NQ = DOUT / 2;
                const uint2* y0 = (const uint2*)(y + r0 * DOUT);
                uint2 c0[NQ];
#pragma unroll
                for (int q = 0; q < NQ; ++q) c0[q] = y0[q];
                uint2 c1[NQ];
                if (two) {
                    p1 = codes[i2];
                    size_t r1 = (size_t)(p1 & 0x3FFFFu);
                    const uint2* y1 = (const uint2*)(y + r1 * DOUT);
#pragma unroll
                    for (int q = 0; q < NQ; ++q) c1[q] = y1[q];
                    a1 = &acc[(p1 >> 18) * ST];
                }
#pragma unroll
                for (int q = 0; q < NQ; ++q) {
                    if (c0[q].x > a0[q * 2 + 0]) atomicMax(&a0[q * 2 + 0], c0[q].x);
                    if (c0[q].y > a0[q * 2 + 1]) atomicMax(&a0[q * 2 + 1], c0[q].y);
                }
                if (two) {
#pragma unroll
                    for (int q = 0; q < NQ; ++q) {
                        if (c1[q].x > a1[q * 2 + 0]) atomicMax(&a1[q * 2 + 0], c1[q].x);
                        if (c1[q].y > a1[q * 2 + 1]) atomicMax(&a1[q * 2 + 1], c1[q].y);
                    }
                }
            }
        }
        __syncthreads();   // band phase barrier (once total when PHASES==1)
    }

    // decode + tanh in place (float bits through the same padded layout)
    float* hsf = (float*)acc;
    for (int idx = tid; idx < nloc * DOUT; idx += 512) {
        int lc = idx / DOUT;
        int f  = idx - lc * DOUT;
        hsf[lc * ST + f] = tanhf(dcs[lc] * fdec(acc[lc * ST + f]) + bs[f]);
    }
    __syncthreads();

    if constexpr (!FINAL) {
        unsigned int* outu = (unsigned int*)outp;
        for (int idx = tid; idx < nloc * DNEXT; idx += 512) {
            int lc = idx / DNEXT;
            int j = idx - lc * DNEXT;
            float a = 0.f;
#pragma unroll
            for (int k = 0; k < DOUT; ++k) a += hsf[lc * ST + k] * Ws[k * DNEXT + j];
            outu[(size_t)node0 * DNEXT + idx] = fenc(dcs[lc] * a);
        }
    } else {
        for (int lc = tid; lc < nloc; lc += 512) {
            float h0 = hsf[lc * ST], h1 = hsf[lc * ST + 1];
            float2 ho; ho.x = h0; ho.y = h1;
            ((float2*)hout)[node0 + lc] = ho;
            float4 o;
            o.x = h0 * Ws[0] + h1 * Ws[DNEXT + 0] + bcls[0];
            o.y = h0 * Ws[1] + h1 * Ws[DNEXT + 1] + bcls[1];
            o.z = h0 * Ws[2] + h1 * Ws[DNEXT + 2] + bcls[2];
            o.w = h0 * Ws[3] + h1 * Ws[DNEXT + 3] + bcls[3];
            ((float4*)outp)[node0 + lc] = o;
        }
    }
}

extern "C" void kernel_launch(void* const* d_in, const int* in_sizes, int n_in,
                              void* d_out, int out_size, void* d_ws, size_t ws_size,
                              hipStream_t stream) {
    const float* x  = (const float*)d_in[0];
    const int*   ei = (const int*)d_in[1];
    const int* row = ei;            // edge_index[0] = source
    const int* col = ei + EE;       // edge_index[1] = target
    const float* W1 = (const float*)d_in[2];  const float* b1 = (const float*)d_in[3];
    const float* W2 = (const float*)d_in[4];  const float* b2 = (const float*)d_in[5];
    const float* W3 = (const float*)d_in[6];  const float* b3 = (const float*)d_in[7];
    const float* W4 = (const float*)d_in[8];  const float* b4 = (const float*)d_in[9];
    const float* W5 = (const float*)d_in[10]; const float* b5 = (const float*)d_in[11];
    const float* Wc = (const float*)d_in[12]; const float* bc = (const float*)d_in[13];
    float* out = (float*)d_out;

    // ---- workspace carve (identical offsets to r10, tripwire-proven) ----
    // pairs is dead before matmul128_y writes bufB -> alias them. codes persists all layers.
    char* ws = (char*)d_ws;
    float*        dinv       = (float*)(ws + 0);                //    800,000
    int*          bandoffs   = (int*)(ws + 800000);             //     81,328 (NBKT*(NRB+1)) -> pad 81,408
    int*          bbase      = (int*)(ws + 881408);             //      3,132 -> pad 3,200
    int*          btot       = (int*)(ws + 884608);             //      3,128 -> pad 3,200
    int*          blkhist    = (int*)(ws + 887808);             //  1,601,536 (GRID_A*NBKT ints)
    unsigned int* codes      = (unsigned int*)(ws + 2489344);   // 25,600,000
    unsigned int* pairs      = (unsigned int*)(ws + 28089344);  // 25,600,000
    unsigned int* bufB       = (unsigned int*)(ws + 28089344);  // (aliases pairs; y1/y3/y5, ENCODED)
    unsigned int* bufA       = (unsigned int*)(ws + 53689344);  // 19,200,000 (y2/y4, ENCODED)
    // total: 72,889,344 B

    const int BLK = 256;
    const int gN = (NN + BLK - 1) / BLK;       // 782

    // ---- CSR build: two-level counting sort; adjacency emitted band-major per bucket ----
    count_buckets_kernel<<<GRID_A, BLK_A, 0, stream>>>(col, blkhist);
    scan_cols_kernel<<<NBKT, GRID_A, 0, stream>>>(blkhist, btot);
    scan_btot_kernel<<<1, 1024, 0, stream>>>(btot, bbase);
    place_pairs_kernel<<<GRID_A, BLK_A, 0, stream>>>(row, col, blkhist, bbase, pairs);
    bucket_build_band_kernel<<<NBKT, 512, 0, stream>>>(pairs, bbase, dinv, codes, bandoffs);

    // ---- layer 1 matmul: y1 = fenc(dinv * (x @ W1)), [N,24] encoded ----
    matmul128_y_kernel<<<gN, BLK, 0, stream>>>(x, W1, dinv, bufB, NN);

    // ---- layer 1 gather + layer-2 matmul fused: y2 [N,12] encoded (banded: y1 19.2MB) ----
    gather_band_kernel<24, 12, false, NRB><<<NBKT, 512, 0, stream>>>(
        codes, bandoffs, dinv, bufB, b1, W2, nullptr, (float*)bufA, nullptr);
    // ---- layer 2 gather + layer-3 matmul fused: y3 [N,6] encoded (banded: y2 9.6MB) ----
    gather_band_kernel<12, 6, false, NRB><<<NBKT, 512, 0, stream>>>(
        codes, bandoffs, dinv, bufA, b2, W3, nullptr, (float*)bufB, nullptr);
    // ---- layer 3 gather + layer-4 matmul fused: y4 [N,4] encoded (banded: y3 4.8MB) ----
    gather_band_kernel<6, 4, false, NRB><<<NBKT, 512, 0, stream>>>(
        codes, bandoffs, dinv, bufB, b3, W4, nullptr, (float*)bufA, nullptr);
    // ---- layer 4 gather + layer-5 matmul fused: y5 [N,2] encoded (single-phase: y4 3.2MB L2-fit) ----
    gather_band_kernel<4, 2, false, 1><<<NBKT, 512, 0, stream>>>(
        codes, bandoffs, dinv, bufA, b4, W5, nullptr, (float*)bufB, nullptr);
    // ---- layer 5 gather + classifier fused: out [N,4], h [N,2] (single-phase: y5 1.6MB L2-fit) ----
    gather_band_kernel<2, 4, true, 1><<<NBKT, 512, 0, stream>>>(
        codes, bandoffs, dinv, bufB, b5, Wc, bc, out, out + (size_t)NN * 4);
}

// Round 13
// 674.524 us; speedup vs baseline: 1.0321x; 1.0047x over previous
//
#include <hip/hip_runtime.h>
#include <cmath>

#define NN 200000
#define EE 6400000
#define NLOC 196          // nodes per bucket (non-pow2: bucket = col / NLOC via magic-mul)
#define NBKT 1024         // buckets; 1024 blocks = EXACTLY 4 blocks/CU on 256 CUs (no tail)
#define GRID_A 512        // blocks in phase-A kernels (MUST match scan width)
#define BLK_A 256
#define RB_SHIFT 13       // row band = row >> 13 (8192 rows/band; y1 slice 0.79 MB, L2-fit)
#define NRB 25            // ceil(200000 / 8192)

// monotone float<->uint encoding: enc preserves order under unsigned max.
// Inter-layer y buffers are stored PRE-ENCODED: the gather hot loop does zero
// per-edge encode VALU; guarded LDS atomicMax on raw loaded words.
__device__ __forceinline__ unsigned int fenc(float f) {
    unsigned int u = __float_as_uint(f);
    return (u & 0x80000000u) ? ~u : (u | 0x80000000u);
}
__device__ __forceinline__ float fdec(unsigned int u) {
    unsigned int v = (u & 0x80000000u) ? (u & 0x7FFFFFFFu) : ~u;
    return __uint_as_float(v);
}

// =============== Phase A: bucket edges by col/NLOC (counting sort, LDS atomics only) ===============

__global__ __launch_bounds__(BLK_A) void count_buckets_kernel(const int* __restrict__ col,
                                                              int* __restrict__ blkhist) {
    __shared__ int h[NBKT];
    for (int t = threadIdx.x; t < NBKT; t += BLK_A) h[t] = 0;
    __syncthreads();
    const int4* col4 = (const int4*)col;
    for (int i = blockIdx.x * BLK_A + threadIdx.x; i < EE / 4; i += GRID_A * BLK_A) {
        int4 c = col4[i];
        atomicAdd(&h[c.x / NLOC], 1);
        atomicAdd(&h[c.y / NLOC], 1);
        atomicAdd(&h[c.z / NLOC], 1);
        atomicAdd(&h[c.w / NLOC], 1);
    }
    __syncthreads();
    for (int t = threadIdx.x; t < NBKT; t += BLK_A) blkhist[blockIdx.x * NBKT + t] = h[t];
}

__global__ __launch_bounds__(GRID_A) void scan_cols_kernel(int* __restrict__ blkhist,
                                                           int* __restrict__ btot) {
    __shared__ int sc[GRID_A];
    int bkt = blockIdx.x, t = threadIdx.x;
    int v = blkhist[t * NBKT + bkt];
    sc[t] = v;
    __syncthreads();
    for (int off = 1; off < GRID_A; off <<= 1) {
        int add = (t >= off) ? sc[t - off] : 0;
        __syncthreads();
        sc[t] += add;
        __syncthreads();
    }
    blkhist[t * NBKT + bkt] = sc[t] - v;  // exclusive along blocks
    if (t == GRID_A - 1) btot[bkt] = sc[t];
}

__global__ __launch_bounds__(1024) void scan_btot_kernel(const int* __restrict__ btot,
                                                         int* __restrict__ bbase) {
    __shared__ int sc[1024];
    int t = threadIdx.x;
    int v = (t < NBKT) ? btot[t] : 0;
    sc[t] = v;
    __syncthreads();
    for (int off = 1; off < 1024; off <<= 1) {
        int add = (t >= off) ? sc[t - off] : 0;
        __syncthreads();
        sc[t] += add;
        __syncthreads();
    }
    if (t < NBKT) bbase[t] = sc[t] - v;
    if (t == NBKT - 1) bbase[NBKT] = sc[t];  // total = EE
}

// A3: place packed codes (int4 edge loads). code = (col - b*NLOC)<<18 | row  (row < 2^18, lc < 256)
__global__ __launch_bounds__(BLK_A) void place_pairs_kernel(const int* __restrict__ row,
                                                            const int* __restrict__ col,
                                                            const int* __restrict__ blkhist,
                                                            const int* __restrict__ bbase,
                                                            unsigned int* __restrict__ pairs) {
    __shared__ int cur[NBKT];
    for (int t = threadIdx.x; t < NBKT; t += BLK_A)
        cur[t] = bbase[t] + blkhist[blockIdx.x * NBKT + t];
    __syncthreads();
    const int4* col4 = (const int4*)col;
    const int4* row4 = (const int4*)row;
    for (int i = blockIdx.x * BLK_A + threadIdx.x; i < EE / 4; i += GRID_A * BLK_A) {
        int4 c = col4[i];
        int4 r = row4[i];
        int b0 = c.x / NLOC;
        int p0 = atomicAdd(&cur[b0], 1);
        pairs[p0] = (unsigned int)r.x | ((unsigned int)(c.x - b0 * NLOC) << 18);
        int b1 = c.y / NLOC;
        int p1 = atomicAdd(&cur[b1], 1);
        pairs[p1] = (unsigned int)r.y | ((unsigned int)(c.y - b1 * NLOC) << 18);
        int b2 = c.z / NLOC;
        int p2 = atomicAdd(&cur[b2], 1);
        pairs[p2] = (unsigned int)r.z | ((unsigned int)(c.z - b2 * NLOC) << 18);
        int b3 = c.w / NLOC;
        int p3 = atomicAdd(&cur[b3], 1);
        pairs[p3] = (unsigned int)r.w | ((unsigned int)(c.w - b3 * NLOC) << 18);
    }
}

// A4: per-bucket counting sort into BAND-MAJOR order (band = row>>RB_SHIFT).
__global__ __launch_bounds__(512) void bucket_build_band_kernel(const unsigned int* __restrict__ pairs,
                                                                const int* __restrict__ bbase,
                                                                float* __restrict__ dinv,
                                                                unsigned int* __restrict__ codes,
                                                                int* __restrict__ bandoffs) {
    __shared__ int bin[NLOC * NRB];   // 4900: flat band-major, linear n = bb*NLOC + lc
    __shared__ int sc[512];
    int b = blockIdx.x, tid = threadIdx.x;
    int base = bbase[b], end = bbase[b + 1];
    int node0 = b * NLOC;
    int nloc = NN - node0; if (nloc > NLOC) nloc = NLOC;   // may be <=0 for trailing empty buckets

    for (int t = tid; t < NLOC * NRB; t += 512) bin[t] = 0;
    __syncthreads();
    for (int i = base + tid; i < end; i += 512) {
        unsigned int p = pairs[i];
        int lc = p >> 18;
        int rw = (int)(p & 0x3FFFFu);
        atomicAdd(&bin[(rw >> RB_SHIFT) * NLOC + lc], 1);
    }
    __syncthreads();

    // degree -> dinv (read before positions overwrite bins)
    if (tid < nloc) {
        int d = 0;
#pragma unroll
        for (int bb = 0; bb < NRB; ++bb) d += bin[bb * NLOC + tid];
        dinv[node0 + tid] = rsqrtf((float)(d + 1));  // +1 self loop
    }
    __syncthreads();

    // exclusive scan of the flat 4900 array: thread t<NLOC owns chunk [t*NRB, t*NRB+NRB)
    int tot = 0;
    if (tid < NLOC) {
#pragma unroll
        for (int i = 0; i < NRB; ++i) tot += bin[tid * NRB + i];
    }
    sc[tid] = tot;
    __syncthreads();
    for (int off = 1; off < 512; off <<= 1) {
        int add = (tid >= off) ? sc[tid - off] : 0;
        __syncthreads();
        sc[tid] += add;
        __syncthreads();
    }
    if (tid < NLOC) {
        int run = base + sc[tid] - tot;   // global exclusive base of this chunk
#pragma unroll
        for (int i = 0; i < NRB; ++i) {
            int c = bin[tid * NRB + i];
            bin[tid * NRB + i] = run;     // becomes placement cursor
            run += c;
        }
    }
    __syncthreads();

    if (tid < NRB) bandoffs[b * (NRB + 1) + tid] = bin[tid * NLOC];
    if (tid == 0) bandoffs[b * (NRB + 1) + NRB] = end;
    __syncthreads();

    for (int i = base + tid; i < end; i += 512) {
        unsigned int p = pairs[i];
        int lc = p >> 18;
        int rw = (int)(p & 0x3FFFFu);
        int pos = atomicAdd(&bin[(rw >> RB_SHIFT) * NLOC + lc], 1);
        codes[pos] = p;
    }
}

// =============== layer-1 matmul, epilogue premultiplies dinv AND ENCODES: y = fenc(dinv*(x@W)) =======
__global__ void matmul128_y_kernel(const float* __restrict__ x, const float* __restrict__ W,
                                   const float* __restrict__ dinv, unsigned int* __restrict__ y, int n) {
    __shared__ float Ws[128 * 24];
    for (int t = threadIdx.x; t < 128 * 24; t += blockDim.x) Ws[t] = W[t];
    __syncthreads();
    int i = blockIdx.x * blockDim.x + threadIdx.x;
    if (i >= n) return;
    float acc[24];
#pragma unroll
    for (int j = 0; j < 24; ++j) acc[j] = 0.f;
    const float4* hr = (const float4*)(x + (size_t)i * 128);
#pragma unroll 8
    for (int k4 = 0; k4 < 32; ++k4) {
        float4 hv = hr[k4];
        const float* wk = &Ws[k4 * 4 * 24];
#pragma unroll
        for (int j = 0; j < 24; ++j) acc[j] += hv.x * wk[j];
#pragma unroll
        for (int j = 0; j < 24; ++j) acc[j] += hv.y * wk[24 + j];
#pragma unroll
        for (int j = 0; j < 24; ++j) acc[j] += hv.z * wk[48 + j];
#pragma unroll
        for (int j = 0; j < 24; ++j) acc[j] += hv.w * wk[72 + j];
    }
    float di = dinv[i];
    uint4* orow = (uint4*)(y + (size_t)i * 24);
#pragma unroll
    for (int q = 0; q < 6; ++q) {
        uint4 o;
        o.x = fenc(di * acc[q * 4 + 0]);
        o.y = fenc(di * acc[q * 4 + 1]);
        o.z = fenc(di * acc[q * 4 + 2]);
        o.w = fenc(di * acc[q * 4 + 3]);
        orow[q] = o;
    }
}

// =============== band-phased bucket gather on PRE-ENCODED y: GUARDED ds_max_u32 ======================
// 196-node buckets: 1024 blocks x 512 threads = EXACTLY 4 blocks/CU (1021 active;
// 3 empty exit instantly) -> no overloaded-CU tail (r12: 782 blocks left 14 CUs
// with 4/3 work, kernel ended on them; occupancy 51%). LDS ~21.6KB -> 4 blocks
// co-resident, 32 waves/CU. PHASES template: NRB band phases (lockstep L2 sweep)
// for big y; PHASES=1 (no inner barriers) when y fits per-XCD L2 (y4, y5).
// Hot loop identical to r8/r10/r12: guarded atomics (r6), odd stride (r5),
// pre-encoded y (r8), per-lane whole-row gather (r9 reverted).
template<int DOUT, int DNEXT, bool FINAL, int PHASES>
__global__ __launch_bounds__(512) void gather_band_kernel(const unsigned int* __restrict__ codes,
                                                          const int* __restrict__ bandoffs,
                                                          const float* __restrict__ dinv,
                                                          const unsigned int* __restrict__ y,  // encoded
                                                          const float* __restrict__ bias,
                                                          const float* __restrict__ Wn,
                                                          const float* __restrict__ bcls,
                                                          float* __restrict__ outp,   // encoded when !FINAL
                                                          float* __restrict__ hout) {
    constexpr int ST = DOUT + 1;           // odd stride -> conflict-free random access
    __shared__ unsigned int acc[NLOC * ST];
    __shared__ float dcs[NLOC];
    __shared__ float Ws[DOUT * DNEXT];
    __shared__ float bs[DOUT];
    const int b0 = blockIdx.x;
    const int node0 = b0 * NLOC;
    if (node0 >= NN) return;               // trailing empty buckets (uniform exit, before any barrier)
    const int nloc = (NN - node0 < NLOC) ? (NN - node0) : NLOC;
    const int tid = threadIdx.x;

    if (tid < DOUT * DNEXT) Ws[tid] = Wn[tid];
    if (tid < DOUT) bs[tid] = bias[tid];
    if (tid < nloc) dcs[tid] = dinv[node0 + tid];
    for (int idx = tid; idx < nloc * DOUT; idx += 512) {
        int lc = idx / DOUT;
        int f  = idx - lc * DOUT;
        acc[lc * ST + f] = y[(size_t)node0 * DOUT + idx];   // self-loop seed (already encoded)
    }
    __syncthreads();

    const int* bo = bandoffs + b0 * (NRB + 1);
#pragma unroll 1
    for (int ph = 0; ph < PHASES; ++ph) {
        const int s0 = (PHASES == 1) ? bo[0] : bo[ph];
        const int e  = (PHASES == 1) ? bo[NRB] : bo[ph + 1];
        for (int i = s0 + tid; i < e; i += 1024) {
            const int i2 = i + 512;
            const bool two = (i2 < e);
            unsigned int p0 = codes[i];
            size_t r0 = (size_t)(p0 & 0x3FFFFu);
            unsigned int* a0 = &acc[(p0 >> 18) * ST];
            unsigned int p1 = 0; unsigned int* a1 = nullptr;
            if constexpr (DOUT % 4 == 0) {
                constexpr int NQ = DOUT / 4;
                const uint4* y0 = (const uint4*)(y + r0 * DOUT);
                uint4 c0[NQ];
#pragma unroll
                for (int q = 0; q < NQ; ++q) c0[q] = y0[q];
                uint4 c1[NQ];
                if (two) {
                    p1 = codes[i2];
                    size_t r1 = (size_t)(p1 & 0x3FFFFu);
                    const uint4* y1 = (const uint4*)(y + r1 * DOUT);
#pragma unroll
                    for (int q = 0; q < NQ; ++q) c1[q] = y1[q];
                    a1 = &acc[(p1 >> 18) * ST];
                }
#pragma unroll
                for (int q = 0; q < NQ; ++q) {
                    if (c0[q].x > a0[q * 4 + 0]) atomicMax(&a0[q * 4 + 0], c0[q].x);
                    if (c0[q].y > a0[q * 4 + 1]) atomicMax(&a0[q * 4 + 1], c0[q].y);
                    if (c0[q].z > a0[q * 4 + 2]) atomicMax(&a0[q * 4 + 2], c0[q].z);
                    if (c0[q].w > a0[q * 4 + 3]) atomicMax(&a0[q * 4 + 3], c0[q].w);
                }
                if (two) {
#pragma unroll
                    for (int q = 0; q < NQ; ++q) {
                        if (c1[q].x > a1[q * 4 + 0]) atomicMax(&a1[q * 4 + 0], c1[q].x);
                        if (c1[q].y > a1[q * 4 + 1]) atomicMax(&a1[q * 4 + 1], c1[q].y);
                        if (c1[q].z > a1[q * 4 + 2]) atomicMax(&a1[q * 4 + 2], c1[q].z);
                        if (c1[q].w > a1[q * 4 + 3]) atomicMax(&a1[q * 4 + 3], c1[q].w);
                    }
                }
            } else {
                constexpr int NQ = DOUT / 2;
                const uint2* y0 = (const uint2*)(y + r0 * DOUT);
                uint2 c0[NQ];
#pragma unroll
                for (int q = 0; q < NQ; ++q) c0[q] = y0[q];
                uint2 c1[NQ];
                if (two) {
                    p1 = codes[i2];
                    size_t r1 = (size_t)(p1 & 0x3FFFFu);
                    const uint2* y1 = (const uint2*)(y + r1 * DOUT);
#pragma unroll
                    for (int q = 0; q < NQ; ++q) c1[q] = y1[q];
                    a1 = &acc[(p1 >> 18) * ST];
                }
#pragma unroll
                for (int q = 0; q < NQ; ++q) {
                    if (c0[q].x > a0[q * 2 + 0]) atomicMax(&a0[q * 2 + 0], c0[q].x);
                    if (c0[q].y > a0[q * 2 + 1]) atomicMax(&a0[q * 2 + 1], c0[q].y);
                }
                if (two) {
#pragma unroll
                    for (int q = 0; q < NQ; ++q) {
                        if (c1[q].x > a1[q * 2 + 0]) atomicMax(&a1[q * 2 + 0], c1[q].x);
                        if (c1[q].y > a1[q * 2 + 1]) atomicMax(&a1[q * 2 + 1], c1[q].y);
                    }
                }
            }
        }
        __syncthreads();   // band phase barrier (once total when PHASES==1)
    }

    // decode + tanh in place (float bits through the same padded layout)
    float* hsf = (float*)acc;
    for (int idx = tid; idx < nloc * DOUT; idx += 512) {
        int lc = idx / DOUT;
        int f  = idx - lc * DOUT;
        hsf[lc * ST + f] = tanhf(dcs[lc] * fdec(acc[lc * ST + f]) + bs[f]);
    }
    __syncthreads();

    if constexpr (!FINAL) {
        unsigned int* outu = (unsigned int*)outp;
        for (int idx = tid; idx < nloc * DNEXT; idx += 512) {
            int lc = idx / DNEXT;
            int j = idx - lc * DNEXT;
            float a = 0.f;
#pragma unroll
            for (int k = 0; k < DOUT; ++k) a += hsf[lc * ST + k] * Ws[k * DNEXT + j];
            outu[(size_t)node0 * DNEXT + idx] = fenc(dcs[lc] * a);
        }
    } else {
        for (int lc = tid; lc < nloc; lc += 512) {
            float h0 = hsf[lc * ST], h1 = hsf[lc * ST + 1];
            float2 ho; ho.x = h0; ho.y = h1;
            ((float2*)hout)[node0 + lc] = ho;
            float4 o;
            o.x = h0 * Ws[0] + h1 * Ws[DNEXT + 0] + bcls[0];
            o.y = h0 * Ws[1] + h1 * Ws[DNEXT + 1] + bcls[1];
            o.z = h0 * Ws[2] + h1 * Ws[DNEXT + 2] + bcls[2];
            o.w = h0 * Ws[3] + h1 * Ws[DNEXT + 3] + bcls[3];
            ((float4*)outp)[node0 + lc] = o;
        }
    }
}

extern "C" void kernel_launch(void* const* d_in, const int* in_sizes, int n_in,
                              void* d_out, int out_size, void* d_ws, size_t ws_size,
                              hipStream_t stream) {
    const float* x  = (const float*)d_in[0];
    const int*   ei = (const int*)d_in[1];
    const int* row = ei;            // edge_index[0] = source
    const int* col = ei + EE;       // edge_index[1] = target
    const float* W1 = (const float*)d_in[2];  const float* b1 = (const float*)d_in[3];
    const float* W2 = (const float*)d_in[4];  const float* b2 = (const float*)d_in[5];
    const float* W3 = (const float*)d_in[6];  const float* b3 = (const float*)d_in[7];
    const float* W4 = (const float*)d_in[8];  const float* b4 = (const float*)d_in[9];
    const float* W5 = (const float*)d_in[10]; const float* b5 = (const float*)d_in[11];
    const float* Wc = (const float*)d_in[12]; const float* bc = (const float*)d_in[13];
    float* out = (float*)d_out;

    // ---- workspace carve (73,411,968 B < 73,606,912 proven cap) ----
    // pairs is dead before matmul128_y writes bufB -> alias them. codes persists all layers.
    char* ws = (char*)d_ws;
    float*        dinv       = (float*)(ws + 0);                //    800,000
    int*          bandoffs   = (int*)(ws + 800000);             //    106,496 (NBKT*(NRB+1) ints)
    int*          bbase      = (int*)(ws + 906496);             //      4,100 -> pad 4,224
    int*          btot       = (int*)(ws + 910720);             //      4,096
    int*          blkhist    = (int*)(ws + 914816);             //  2,097,152 (GRID_A*NBKT ints)
    unsigned int* codes      = (unsigned int*)(ws + 3011968);   // 25,600,000
    unsigned int* pairs      = (unsigned int*)(ws + 28611968);  // 25,600,000
    unsigned int* bufB       = (unsigned int*)(ws + 28611968);  // (aliases pairs; y1/y3/y5, ENCODED)
    unsigned int* bufA       = (unsigned int*)(ws + 54211968);  // 19,200,000 (y2/y4, ENCODED)
    // total: 73,411,968 B

    const int BLK = 256;
    const int gN = (NN + BLK - 1) / BLK;       // 782

    // ---- CSR build: two-level counting sort; adjacency emitted band-major per bucket ----
    count_buckets_kernel<<<GRID_A, BLK_A, 0, stream>>>(col, blkhist);
    scan_cols_kernel<<<NBKT, GRID_A, 0, stream>>>(blkhist, btot);
    scan_btot_kernel<<<1, 1024, 0, stream>>>(btot, bbase);
    place_pairs_kernel<<<GRID_A, BLK_A, 0, stream>>>(row, col, blkhist, bbase, pairs);
    bucket_build_band_kernel<<<NBKT, 512, 0, stream>>>(pairs, bbase, dinv, codes, bandoffs);

    // ---- layer 1 matmul: y1 = fenc(dinv * (x @ W1)), [N,24] encoded ----
    matmul128_y_kernel<<<gN, BLK, 0, stream>>>(x, W1, dinv, bufB, NN);

    // ---- layer 1 gather + layer-2 matmul fused: y2 [N,12] encoded (banded: y1 19.2MB) ----
    gather_band_kernel<24, 12, false, NRB><<<NBKT, 512, 0, stream>>>(
        codes, bandoffs, dinv, bufB, b1, W2, nullptr, (float*)bufA, nullptr);
    // ---- layer 2 gather + layer-3 matmul fused: y3 [N,6] encoded (banded: y2 9.6MB) ----
    gather_band_kernel<12, 6, false, NRB><<<NBKT, 512, 0, stream>>>(
        codes, bandoffs, dinv, bufA, b2, W3, nullptr, (float*)bufB, nullptr);
    // ---- layer 3 gather + layer-4 matmul fused: y4 [N,4] encoded (banded: y3 4.8MB) ----
    gather_band_kernel<6, 4, false, NRB><<<NBKT, 512, 0, stream>>>(
        codes, bandoffs, dinv, bufB, b3, W4, nullptr, (float*)bufA, nullptr);
    // ---- layer 4 gather + layer-5 matmul fused: y5 [N,2] encoded (single-phase: y4 3.2MB L2-fit) ----
    gather_band_kernel<4, 2, false, 1><<<NBKT, 512, 0, stream>>>(
        codes, bandoffs, dinv, bufA, b4, W5, nullptr, (float*)bufB, nullptr);
    // ---- layer 5 gather + classifier fused: out [N,4], h [N,2] (single-phase: y5 1.6MB L2-fit) ----
    gather_band_kernel<2, 4, true, 1><<<NBKT, 512, 0, stream>>>(
        codes, bandoffs, dinv, bufB, b5, Wc, bc, out, out + (size_t)NN * 4);
}